// Round 11
// baseline (60.084 us; speedup 1.0000x reference)
//
#include <hip/hip_runtime.h>
#include <math.h>
#include <stdint.h>

#define NS    16
#define HWSZ  409600
#define NF4   102400      // float4s per sample
#define NBIN  128
#define SLW   (3*NBIN + 8) // words per block slice: hist cnt/s1/s2 + 8 scalar slots
#define CAP   4096
#define BCAP  512         // per-block LDS candidate staging
#define SBPS  200         // scan blocks per sample
#define NIT   4           // pipelined iterations per scan block (128 f4 each)
#define GBPS  100         // gather blocks per sample
#define PADI  32          // ints per sample for padded atomic counter (128 B)

typedef unsigned long long u64;
#define AS1 __attribute__((address_space(1)))
#define AS3 __attribute__((address_space(3)))

__device__ __forceinline__ unsigned fkey(float f) {
    unsigned u = __float_as_uint(f);
    if (u == 0x80000000u) u = 0u;                 // canonicalize -0
    return (u & 0x80000000u) ? ~u : (u | 0x80000000u);
}

// bce1: BCE on p; bce2: BCE on sigmoid(50(p-t)); both with 1e-7 clipping
__device__ __forceinline__ void bce_pair(float pv, float tv, bool tc, float& o1, float& o2) {
    float pc = fminf(fmaxf(pv, 1e-7f), 1.0f - 1e-7f);
    float a = tc ? pc : 1.0f - pc;
    o1 = -__logf(a);
    float x = 50.0f * (pv - tv);
    float y = tc ? -x : x;
    float t2 = __expf(-fabsf(y));
    float sp = __logf(1.0f + t2);
    sp = (y > 0.0f) ? y + sp : sp;
    o2 = fminf(sp, 16.118095651f);
}

__device__ __forceinline__ int pbin(float p) {
    int b = (int)(p * (float)NBIN);
    return min(max(b, 0), NBIN - 1);
}

// Wave-parallel descending k-th-largest bin search over a histogram.
__device__ __forceinline__ bool wave_find(const int* __restrict__ h, int nbins, int k,
                                          int* bin_out, int* rank_out) {
    const int lane = threadIdx.x & 63;
    const int CH = nbins >> 6;
    const int topStart = nbins - 1 - lane * CH;
    int s = 0;
    for (int b = 0; b < CH; ++b) s += h[topStart - b];
    int incl = s;
    for (int off = 1; off < 64; off <<= 1) {
        int v = __shfl_up(incl, off, 64);
        if (lane >= off) incl += v;
    }
    int before = incl - s;
    if (before < k && k <= incl) {
        int c = before;
        for (int b = 0; b < CH; ++b) {
            int hb = h[topStart - b];
            c += hb;
            if (c >= k) { *bin_out = topStart - b; *rank_out = k - (c - hb); return true; }
        }
    }
    return false;
}

// ---------------- fat pass: DMA-staged (global_load_lds) pipeline -----------
__global__ void k_scan1(const float* __restrict__ outputs, const float* __restrict__ labels,
                        const float* __restrict__ tmask, const float* __restrict__ gd,
                        float* __restrict__ part) {
    __shared__ float4 sbuf[2][6][128];
    __shared__ int lc[NBIN];
    __shared__ float l1[NBIN], l2[NBIN];
    __shared__ float rf[2][4];
    __shared__ int ri[2][2];
    const int t = threadIdx.x, n = blockIdx.y, lane = t & 63, wid = t >> 6;
    if (t < NBIN) { lc[t] = 0; l1[t] = 0.f; l2[t] = 0.f; }
    __syncthreads();
    const float4* P  = (const float4*)(outputs + (size_t)n * 2 * HWSZ);
    const float4* Th = P + NF4;
    const float4* G  = (const float4*)(labels + (size_t)n * 2 * HWSZ);
    const float4* Gt = G + NF4;
    const float4* T  = (const float4*)(tmask + (size_t)n * HWSZ);
    const float4* D  = (const float4*)(gd + (size_t)n * HWSZ);
    const int i0 = blockIdx.x * (NIT * 128);
    const int wb = t & 64;   // wave-uniform LDS element base (DMA dest: base + lane*16)
    auto stg = [&](int b, int k) {
        const int i = i0 + k * 128 + t;
        __builtin_amdgcn_global_load_lds((const AS1 void*)(P  + i), (AS3 void*)&sbuf[b][0][wb], 16, 0, 0);
        __builtin_amdgcn_global_load_lds((const AS1 void*)(Th + i), (AS3 void*)&sbuf[b][1][wb], 16, 0, 0);
        __builtin_amdgcn_global_load_lds((const AS1 void*)(G  + i), (AS3 void*)&sbuf[b][2][wb], 16, 0, 0);
        __builtin_amdgcn_global_load_lds((const AS1 void*)(Gt + i), (AS3 void*)&sbuf[b][3][wb], 16, 0, 0);
        __builtin_amdgcn_global_load_lds((const AS1 void*)(T  + i), (AS3 void*)&sbuf[b][4][wb], 16, 0, 0);
        __builtin_amdgcn_global_load_lds((const AS1 void*)(D  + i), (AS3 void*)&sbuf[b][5][wb], 16, 0, 0);
    };
    float s3 = 0.f, s4 = 0.f, p1 = 0.f, p2 = 0.f;
    int cp = 0, cn = 0;
    stg(0, 0);
    int cur = 0;
#pragma unroll
    for (int k = 0; k < NIT; ++k) {
        if (k + 1 < NIT) {
            stg(cur ^ 1, k + 1);                       // prefetch next buffer
            asm volatile("s_waitcnt vmcnt(6)" ::: "memory");  // current buffer landed
        } else {
            asm volatile("s_waitcnt vmcnt(0)" ::: "memory");
        }
        __builtin_amdgcn_sched_barrier(0);
        // each thread reads only its own lane-matched slots: no barrier needed
        float4 p = sbuf[cur][0][t], th = sbuf[cur][1][t], g = sbuf[cur][2][t];
        float4 q = sbuf[cur][3][t], m  = sbuf[cur][4][t], d = sbuf[cur][5][t];
        const float* pp = (const float*)&p;  const float* tt = (const float*)&th;
        const float* gg = (const float*)&g;  const float* qq = (const float*)&q;
        const float* mm = (const float*)&m;  const float* dd = (const float*)&d;
#pragma unroll
        for (int e = 0; e < 4; ++e) {
            float pv = pp[e], tv = tt[e], gv = gg[e], qv = qq[e], mv = mm[e], dv = dd[e];
            s3 += fabsf(tv - qv) * dv;
            s4 += dv;
            bool msk = mv > 0.5f, tc = gv > 0.5f;
            if (msk) {
                float o1, o2; bce_pair(pv, tv, tc, o1, o2);
                if (tc) { p1 += o1; p2 += o2; cp++; }
                else {
                    cn++;
                    int b = pbin(pv);
                    atomicAdd(&lc[b], 1);
                    atomicAdd(&l1[b], o1);
                    atomicAdd(&l2[b], o2);
                }
            }
        }
        cur ^= 1;
    }
    for (int off = 32; off; off >>= 1) {
        p1 += __shfl_down(p1, off, 64);
        p2 += __shfl_down(p2, off, 64);
        s3 += __shfl_down(s3, off, 64);
        s4 += __shfl_down(s4, off, 64);
        cp += __shfl_down(cp, off, 64);
        cn += __shfl_down(cn, off, 64);
    }
    if (!lane) {
        rf[wid][0] = p1; rf[wid][1] = p2; rf[wid][2] = s3; rf[wid][3] = s4;
        ri[wid][0] = cp; ri[wid][1] = cn;
    }
    __syncthreads();
    float* slice = part + (size_t)(n * SBPS + blockIdx.x) * SLW;
    int* slice_i = (int*)slice;
    if (t < NBIN) {
        slice_i[t]            = lc[t];
        slice[NBIN + t]       = l1[t];
        slice[2 * NBIN + t]   = l2[t];
    }
    if (!t) {
        slice_i[3 * NBIN + 0] = ri[0][0] + ri[1][0];  // cp
        slice_i[3 * NBIN + 1] = ri[0][1] + ri[1][1];  // cn
        slice[3 * NBIN + 2]   = rf[0][0] + rf[1][0];  // p1
        slice[3 * NBIN + 3]   = rf[0][1] + rf[1][1];  // p2
        slice[3 * NBIN + 4]   = rf[0][2] + rf[1][2];  // s3
        slice[3 * NBIN + 5]   = rf[0][3] + rf[1][3];  // s4
    }
}

// ---------------- per-sample: reduce partials + select + suffix sums --------
// modes: 0 = threshold in boundary bin; 1 = pos only; 2 = all masked; 3 = all neg+pos
__global__ void k_sel1(const float* __restrict__ part,
                       int* __restrict__ mode, int* __restrict__ b1o, int* __restrict__ k1o,
                       int* __restrict__ poss,
                       double* __restrict__ psum, double* __restrict__ ab1,
                       double* __restrict__ ab2, int* __restrict__ abc,
                       double* __restrict__ s3s, double* __restrict__ s4s) {
    __shared__ int lc[NBIN];
    __shared__ float l1[NBIN], l2[NBIN];
    __shared__ double sdr[4][4];
    __shared__ int sir[4][2];
    __shared__ double rda[4], rdb[4];
    __shared__ int ric[4];
    __shared__ int sb1, sk1, s_md, s_k;
    const int n = blockIdx.x, t = threadIdx.x, lane = t & 63, wid = t >> 6;
    const float* base = part + (size_t)n * SBPS * SLW;
    // ---- scalar reduction over SBPS block slices
    double p1 = 0.0, p2 = 0.0, s3 = 0.0, s4 = 0.0;
    int cp = 0, cn = 0;
    if (t < SBPS) {
        const float* sl = base + (size_t)t * SLW;
        const int* sli = (const int*)sl;
        cp = sli[3 * NBIN + 0]; cn = sli[3 * NBIN + 1];
        p1 = (double)sl[3 * NBIN + 2]; p2 = (double)sl[3 * NBIN + 3];
        s3 = (double)sl[3 * NBIN + 4]; s4 = (double)sl[3 * NBIN + 5];
    }
    for (int off = 32; off; off >>= 1) {
        p1 += __shfl_down(p1, off, 64);
        p2 += __shfl_down(p2, off, 64);
        s3 += __shfl_down(s3, off, 64);
        s4 += __shfl_down(s4, off, 64);
        cp += __shfl_down(cp, off, 64);
        cn += __shfl_down(cn, off, 64);
    }
    if (!lane) {
        sdr[wid][0] = p1; sdr[wid][1] = p2; sdr[wid][2] = s3; sdr[wid][3] = s4;
        sir[wid][0] = cp; sir[wid][1] = cn;
    }
    if (t < NBIN) { lc[t] = 0; l1[t] = 0.f; l2[t] = 0.f; }
    __syncthreads();
    if (!t) {
        int pos = 0, neg = 0;
        double a = 0.0, b = 0.0, c = 0.0, d = 0.0;
        for (int w = 0; w < 4; ++w) {
            pos += sir[w][0]; neg += sir[w][1];
            a += sdr[w][0]; b += sdr[w][1]; c += sdr[w][2]; d += sdr[w][3];
        }
        int k = pos * 3; if (k > neg) k = neg;
        int md = (pos == 0) ? 2 : ((k == 0) ? 1 : ((k == neg) ? 3 : 0));
        mode[n] = md;
        poss[n] = pos;
        psum[n * 2 + 0] = a;
        psum[n * 2 + 1] = b;
        s3s[n] = c;
        s4s[n] = d;
        s_md = md; s_k = k;
    }
    __syncthreads();
    const int md = s_md, k = s_k;
    if (md == 1) { if (!t) { ab1[n] = 0.0; ab2[n] = 0.0; abc[n] = 0; } return; }
    // ---- histogram reduction: 2 thread-groups cover 100 slices each
    {
        const int bin = t & (NBIN - 1);
        const int grp = t >> 7;               // 0..1
        const int j0 = grp * (SBPS / 2);
        const int j1 = j0 + (SBPS / 2);
        int c = 0; float a = 0.f, b = 0.f;
        for (int j = j0; j < j1; ++j) {
            const float* sl = base + (size_t)j * SLW;
            c += ((const int*)sl)[bin];
            a += sl[NBIN + bin];
            b += sl[2 * NBIN + bin];
        }
        atomicAdd(&lc[bin], c);
        atomicAdd(&l1[bin], a);
        atomicAdd(&l2[bin], b);
    }
    __syncthreads();
    int B = -1;   // md==2 or md==3: sum ALL bins
    if (md == 0) {
        if (t < 64) { int bin, r; if (wave_find(lc, NBIN, k, &bin, &r)) { sb1 = bin; sk1 = r; } }
        __syncthreads();
        B = sb1;
        if (!t) { b1o[n] = sb1; k1o[n] = sk1; }
    }
    double a1 = 0.0, a2 = 0.0; int ac = 0;
    if (t < NBIN && t > B) { a1 = (double)l1[t]; a2 = (double)l2[t]; ac = lc[t]; }
    for (int off = 32; off; off >>= 1) {
        a1 += __shfl_down(a1, off, 64);
        a2 += __shfl_down(a2, off, 64);
        ac += __shfl_down(ac, off, 64);
    }
    if (!lane) { rda[wid] = a1; rdb[wid] = a2; ric[wid] = ac; }
    __syncthreads();
    if (!t) {
        double ra = 0.0, rb = 0.0; int rc = 0;
        for (int w = 0; w < 4; ++w) { ra += rda[w]; rb += rdb[w]; rc += ric[w]; }
        ab1[n] = ra; ab2[n] = rb; abc[n] = rc;
    }
}

// ---------------- boundary-bin gather: LDS-staged, 1 atomic per block -------
__global__ void k_gather(const float* __restrict__ outputs, const float* __restrict__ labels,
                         const float* __restrict__ tmask,
                         const int* __restrict__ mode, const int* __restrict__ b1a,
                         int* __restrict__ cand_cnt, unsigned* __restrict__ ck,
                         float* __restrict__ cv1, float* __restrict__ cv2) {
    const int n = blockIdx.y;
    if (mode[n] != 0) return;   // modes 1/2/3 need no boundary refinement
    const int b1n = b1a[n];
    __shared__ int lcnt, lbase;
    __shared__ unsigned lsk[BCAP];
    __shared__ float lv1[BCAP], lv2[BCAP];
    const int t = threadIdx.x;
    if (!t) lcnt = 0;
    __syncthreads();
    const float* bp = outputs + (size_t)n * 2 * HWSZ;
    const float4* P = (const float4*)bp;
    const float* Thp = bp + HWSZ;
    const float4* G = (const float4*)(labels + (size_t)n * 2 * HWSZ);
    const float4* T = (const float4*)(tmask + (size_t)n * HWSZ);
    const int stride = GBPS * 256;
    for (int i4 = blockIdx.x * 256 + t; i4 < NF4; i4 += stride) {
        float4 p = P[i4], g = G[i4], m = T[i4];
        const float* pp = (const float*)&p;
        const float* gg = (const float*)&g;
        const float* mm = (const float*)&m;
#pragma unroll
        for (int e = 0; e < 4; ++e) {
            bool cand = (gg[e] <= 0.5f) && (mm[e] > 0.5f) && (pbin(pp[e]) == b1n);
            if (cand) {
                float o1, o2; bce_pair(pp[e], Thp[4 * i4 + e], false, o1, o2);
                int idx = atomicAdd(&lcnt, 1);
                if (idx < BCAP) { lsk[idx] = fkey(pp[e]); lv1[idx] = o1; lv2[idx] = o2; }
                else {
                    int gi = atomicAdd(&cand_cnt[n * PADI], 1);   // rare overflow path
                    if (gi < CAP) { ck[n * CAP + gi] = fkey(pp[e]); cv1[n * CAP + gi] = o1; cv2[n * CAP + gi] = o2; }
                }
            }
        }
    }
    __syncthreads();
    const int cnt = min(lcnt, BCAP);
    if (!t && cnt) lbase = atomicAdd(&cand_cnt[n * PADI], cnt);
    __syncthreads();
    if (cnt) {
        const int bb = lbase;
        for (int i = t; i < cnt; i += 256) {
            int gi = bb + i;
            if (gi < CAP) { ck[n * CAP + gi] = lsk[i]; cv1[n * CAP + gi] = lv1[i]; cv2[n * CAP + gi] = lv2[i]; }
        }
    }
}

// ---------------- per-sample finalize (plain stores) ------------------------
__global__ void k_final(const float* __restrict__ outputs, const float* __restrict__ labels,
                        const float* __restrict__ tmask,
                        const int* __restrict__ mode, const int* __restrict__ b1a,
                        const int* __restrict__ k1a, const int* __restrict__ poss,
                        const int* __restrict__ cand_cnt, const unsigned* __restrict__ ck,
                        const float* __restrict__ cv1, const float* __restrict__ cv2,
                        const double* __restrict__ psum, const double* __restrict__ ab1,
                        const double* __restrict__ ab2, const int* __restrict__ abc,
                        double* __restrict__ res) {
    __shared__ unsigned sk[CAP];
    __shared__ float sv1[CAP], sv2[CAP];
    __shared__ int h[2048];
    __shared__ int sbh, srh, sbm, srm, sbl;
    __shared__ double rd[4][2];
    __shared__ int ri[4];
    const int n = blockIdx.x, t = threadIdx.x;
    const int md = mode[n];
    double f1r = 0.0, f2r = 0.0; int fcr = 0;
    if (md == 0) {
        const int k1 = k1a[n];
        const int cc = cand_cnt[n * PADI];
        float f1 = 0.f, f2 = 0.f; int fc = 0;
        if (cc <= CAP) {
            for (int i = t; i < cc; i += 256) {
                sk[i] = ck[n * CAP + i]; sv1[i] = cv1[n * CAP + i]; sv2[i] = cv2[n * CAP + i];
            }
            for (int i = t; i < 2048; i += 256) h[i] = 0;
            __syncthreads();
            for (int i = t; i < cc; i += 256) atomicAdd(&h[sk[i] >> 21], 1);
            __syncthreads();
            if (t < 64) { int b, r; if (wave_find(h, 2048, k1, &b, &r)) { sbh = b; srh = r; } }
            __syncthreads();
            const unsigned bh = (unsigned)sbh; const int r2 = srh;
            for (int i = t; i < 2048; i += 256) h[i] = 0;
            __syncthreads();
            for (int i = t; i < cc; i += 256)
                if ((sk[i] >> 21) == bh) atomicAdd(&h[(sk[i] >> 10) & 0x7FFu], 1);
            __syncthreads();
            if (t < 64) { int b, r; if (wave_find(h, 2048, r2, &b, &r)) { sbm = b; srm = r; } }
            __syncthreads();
            const unsigned bm = (unsigned)sbm; const int r3 = srm;
            for (int i = t; i < 1024; i += 256) h[i] = 0;
            __syncthreads();
            for (int i = t; i < cc; i += 256)
                if ((sk[i] >> 10) == ((bh << 11) | bm)) atomicAdd(&h[sk[i] & 0x3FFu], 1);
            __syncthreads();
            if (t < 64) { int b, r; if (wave_find(h, 1024, r3, &b, &r)) sbl = b; }
            __syncthreads();
            const unsigned thr_key = (bh << 21) | (bm << 10) | (unsigned)sbl;
            for (int i = t; i < cc; i += 256)
                if (sk[i] >= thr_key) { f1 += sv1[i]; f2 += sv2[i]; fc++; }
        } else {
            // slow path: rescan boundary bin from global (general insurance)
            const int b1n = b1a[n];
            const float* Pp = outputs + (size_t)n * 2 * HWSZ;
            const float* Thp = Pp + HWSZ;
            const float* Gp = labels + (size_t)n * 2 * HWSZ;
            const float* Tp = tmask + (size_t)n * HWSZ;
            for (int i = t; i < 2048; i += 256) h[i] = 0;
            __syncthreads();
            for (int i = t; i < HWSZ; i += 256) {
                float pv = Pp[i];
                if (Gp[i] <= 0.5f && Tp[i] > 0.5f && pbin(pv) == b1n)
                    atomicAdd(&h[fkey(pv) >> 21], 1);
            }
            __syncthreads();
            if (t < 64) { int b, r; if (wave_find(h, 2048, k1, &b, &r)) { sbh = b; srh = r; } }
            __syncthreads();
            const unsigned bh = (unsigned)sbh; const int r2 = srh;
            for (int i = t; i < 2048; i += 256) h[i] = 0;
            __syncthreads();
            for (int i = t; i < HWSZ; i += 256) {
                float pv = Pp[i]; unsigned key = fkey(pv);
                if (Gp[i] <= 0.5f && Tp[i] > 0.5f && pbin(pv) == b1n && (key >> 21) == bh)
                    atomicAdd(&h[(key >> 10) & 0x7FFu], 1);
            }
            __syncthreads();
            if (t < 64) { int b, r; if (wave_find(h, 2048, r2, &b, &r)) { sbm = b; srm = r; } }
            __syncthreads();
            const unsigned bm = (unsigned)sbm; const int r3 = srm;
            for (int i = t; i < 1024; i += 256) h[i] = 0;
            __syncthreads();
            for (int i = t; i < HWSZ; i += 256) {
                float pv = Pp[i]; unsigned key = fkey(pv);
                if (Gp[i] <= 0.5f && Tp[i] > 0.5f && pbin(pv) == b1n && (key >> 10) == ((bh << 11) | bm))
                    atomicAdd(&h[key & 0x3FFu], 1);
            }
            __syncthreads();
            if (t < 64) { int b, r; if (wave_find(h, 1024, r3, &b, &r)) sbl = b; }
            __syncthreads();
            const unsigned thr_key = (bh << 21) | (bm << 10) | (unsigned)sbl;
            for (int i = t; i < HWSZ; i += 256) {
                float pv = Pp[i];
                if (Gp[i] <= 0.5f && Tp[i] > 0.5f && pbin(pv) == b1n && fkey(pv) >= thr_key) {
                    float b1v, b2v; bce_pair(pv, Thp[i], false, b1v, b2v);
                    f1 += b1v; f2 += b2v; fc++;
                }
            }
        }
        double v0 = f1, v1 = f2;
        for (int off = 32; off; off >>= 1) {
            v0 += __shfl_down(v0, off, 64);
            v1 += __shfl_down(v1, off, 64);
            fc += __shfl_down(fc, off, 64);
        }
        const int lane = t & 63, wid = t >> 6;
        if (!lane) { rd[wid][0] = v0; rd[wid][1] = v1; ri[wid] = fc; }
        __syncthreads();
        if (!t) {
            f1r = rd[0][0] + rd[1][0] + rd[2][0] + rd[3][0];
            f2r = rd[0][1] + rd[1][1] + rd[2][1] + rd[3][1];
            fcr = ri[0] + ri[1] + ri[2] + ri[3];
        }
    }
    if (!t) {
        res[n * 3 + 0] = psum[n * 2 + 0] + ab1[n] + f1r;
        res[n * 3 + 1] = psum[n * 2 + 1] + ab2[n] + f2r;
        res[n * 3 + 2] = (double)poss[n] + (double)abc[n] + (double)fcr;
    }
}

__global__ void k_fin(const double* __restrict__ res, const double* __restrict__ s3s,
                      const double* __restrict__ s4s, float* __restrict__ out) {
    if (threadIdx.x != 0 || blockIdx.x != 0) return;
    double A = 0.0, Bb = 0.0, C = 0.0, S3 = 0.0, S4 = 0.0;
    for (int n = 0; n < NS; ++n) {
        A += res[n * 3 + 0]; Bb += res[n * 3 + 1]; C += res[n * 3 + 2];
        S3 += s3s[n]; S4 += s4s[n];
    }
    double lp = (C > 0.0) ? A / C : 0.0;
    double lb = (C > 0.0) ? Bb / C : 0.0;
    double lt = S3 / (S4 + 1e-6);
    out[0] = (float)(lp + lb + 10.0 * lt);
    out[1] = (float)lp;
    out[2] = (float)lb;
    out[3] = (float)lt;
}

extern "C" void kernel_launch(void* const* d_in, const int* in_sizes, int n_in,
                              void* d_out, int out_size, void* d_ws, size_t ws_size,
                              hipStream_t stream) {
    const float* outputs = (const float*)d_in[0];
    const float* labels  = (const float*)d_in[1];
    const float* tmask   = (const float*)d_in[2];
    const float* gd      = (const float*)d_in[3];
    float* out = (float*)d_out;

    char* ws = (char*)d_ws;
    double* s3s   = (double*)ws;                 // NS
    double* s4s   = s3s + NS;                    // NS
    double* psum  = s4s + NS;                    // NS*2
    double* ab1   = psum + NS * 2;               // NS
    double* ab2   = ab1 + NS;                    // NS
    double* res   = ab2 + NS;                    // NS*3
    int* abc      = (int*)(res + NS * 3);        // NS
    int* mode     = abc + NS;                    // NS
    int* b1       = mode + NS;                   // NS
    int* k1       = b1 + NS;                     // NS
    int* poss     = k1 + NS;                     // NS
    int* cand_cnt = poss + NS;                   // NS*PADI (padded counters)
    float* part   = (float*)(cand_cnt + NS * PADI);  // NS*SBPS*SLW (fully written)
    unsigned* ck  = (unsigned*)(part + (size_t)NS * SBPS * SLW);  // NS*CAP
    float* cv1    = (float*)(ck + NS * CAP);
    float* cv2    = cv1 + NS * CAP;
    (void)cv2; (void)ws_size; (void)in_sizes; (void)n_in; (void)out_size;

    // only the padded counters need zeroing; everything else is overwritten
    hipMemsetAsync(cand_cnt, 0, NS * PADI * sizeof(int), stream);

    k_scan1<<<dim3(SBPS, NS), 128, 0, stream>>>(outputs, labels, tmask, gd, part);
    k_sel1<<<NS, 256, 0, stream>>>(part, mode, b1, k1, poss, psum, ab1, ab2, abc, s3s, s4s);
    k_gather<<<dim3(GBPS, NS), 256, 0, stream>>>(outputs, labels, tmask, mode, b1,
                                                 cand_cnt, ck, cv1, cv2);
    k_final<<<NS, 256, 0, stream>>>(outputs, labels, tmask, mode, b1, k1, poss, cand_cnt,
                                    ck, cv1, cv2, psum, ab1, ab2, abc, res);
    k_fin<<<1, 64, 0, stream>>>(res, s3s, s4s, out);
}

// Round 12
// 44.708 us; speedup vs baseline: 1.3439x; 1.3439x over previous
//
#include <hip/hip_runtime.h>
#include <math.h>
#include <stdint.h>

#define NS    16
#define HWSZ  409600
#define NF4   102400      // float4s per sample
#define NBIN  128
#define SLW   (NBIN + 8)  // slice: count hist + 8 scalars (cp,cn,p1,p2,n1,n2,s3,s4)
#define CAP   4096
#define BCAP  512         // per-block LDS candidate staging
#define SBPS  100         // scan blocks per sample (4 pipelined iters of 256 f4)
#define GBPS  100         // gather blocks per sample
#define PADI  32          // ints per sample for padded atomic counter (128 B)

typedef unsigned long long u64;
typedef float f32x4 __attribute__((ext_vector_type(4)));

__device__ __forceinline__ unsigned fkey(float f) {
    unsigned u = __float_as_uint(f);
    if (u == 0x80000000u) u = 0u;                 // canonicalize -0
    return (u & 0x80000000u) ? ~u : (u | 0x80000000u);
}

// bce1: BCE on p; bce2: BCE on sigmoid(50(p-t)); both with 1e-7 clipping
__device__ __forceinline__ void bce_pair(float pv, float tv, bool tc, float& o1, float& o2) {
    float pc = fminf(fmaxf(pv, 1e-7f), 1.0f - 1e-7f);
    float a = tc ? pc : 1.0f - pc;
    o1 = -__logf(a);
    float x = 50.0f * (pv - tv);
    float y = tc ? -x : x;
    float t2 = __expf(-fabsf(y));
    float sp = __logf(1.0f + t2);
    sp = (y > 0.0f) ? y + sp : sp;
    o2 = fminf(sp, 16.118095651f);
}

__device__ __forceinline__ int pbin(float p) {
    int b = (int)(p * (float)NBIN);
    return min(max(b, 0), NBIN - 1);
}

// Wave-parallel descending k-th-largest bin search over a histogram.
__device__ __forceinline__ bool wave_find(const int* __restrict__ h, int nbins, int k,
                                          int* bin_out, int* rank_out) {
    const int lane = threadIdx.x & 63;
    const int CH = nbins >> 6;
    const int topStart = nbins - 1 - lane * CH;
    int s = 0;
    for (int b = 0; b < CH; ++b) s += h[topStart - b];
    int incl = s;
    for (int off = 1; off < 64; off <<= 1) {
        int v = __shfl_up(incl, off, 64);
        if (lane >= off) incl += v;
    }
    int before = incl - s;
    if (before < k && k <= incl) {
        int c = before;
        for (int b = 0; b < CH; ++b) {
            int hb = h[topStart - b];
            c += hb;
            if (c >= k) { *bin_out = topStart - b; *rank_out = k - (c - hb); return true; }
        }
    }
    return false;
}

#define GLOAD(dst, addr) \
    asm volatile("global_load_dwordx4 %0, %1, off" : "=v"(dst) : "v"(addr))
#define LOADSET(Sp, St, Sg, Sq, Sm, Sd, idx) do { \
    GLOAD(Sp, P + (idx));  GLOAD(St, Th + (idx)); GLOAD(Sg, G + (idx)); \
    GLOAD(Sq, Gt + (idx)); GLOAD(Sm, T + (idx)); GLOAD(Sd, D + (idx)); } while (0)
#define WAITSET(Sp, St, Sg, Sq, Sm, Sd, N) \
    asm volatile("s_waitcnt vmcnt(" #N ")" \
                 : "+v"(Sp), "+v"(St), "+v"(Sg), "+v"(Sq), "+v"(Sm), "+v"(Sd))

// ---------------- fat pass: slim inner loop (count-only binning) ------------
__global__ void k_scan1(const float* __restrict__ outputs, const float* __restrict__ labels,
                        const float* __restrict__ tmask, const float* __restrict__ gd,
                        float* __restrict__ part) {
    __shared__ int lc[NBIN];
    __shared__ float rf[4][6];
    __shared__ int ri[4][2];
    const int t = threadIdx.x, n = blockIdx.y, lane = t & 63, wid = t >> 6;
    if (t < NBIN) lc[t] = 0;
    __syncthreads();
    const f32x4* P  = (const f32x4*)(outputs + (size_t)n * 2 * HWSZ);
    const f32x4* Th = P + NF4;
    const f32x4* G  = (const f32x4*)(labels + (size_t)n * 2 * HWSZ);
    const f32x4* Gt = G + NF4;
    const f32x4* T  = (const f32x4*)(tmask + (size_t)n * HWSZ);
    const f32x4* D  = (const f32x4*)(gd + (size_t)n * HWSZ);
    const int i0 = blockIdx.x * 1024 + t;         // 4 iterations, stride 256
    float s3 = 0.f, s4 = 0.f, p1 = 0.f, p2 = 0.f, n1 = 0.f, n2 = 0.f;
    int cp = 0, cn = 0;
    auto proc = [&](const f32x4& p, const f32x4& th, const f32x4& g, const f32x4& q,
                    const f32x4& m, const f32x4& d) {
#pragma unroll
        for (int e = 0; e < 4; ++e) {
            float pv = p[e], tv = th[e], gv = g[e], qv = q[e], mv = m[e], dv = d[e];
            s3 += fabsf(tv - qv) * dv;
            s4 += dv;
            bool msk = mv > 0.5f, tc = gv > 0.5f;
            if (msk) {
                float o1, o2; bce_pair(pv, tv, tc, o1, o2);
                if (tc) { p1 += o1; p2 += o2; cp++; }
                else    { n1 += o1; n2 += o2; cn++; atomicAdd(&lc[pbin(pv)], 1); }
            }
        }
    };
    f32x4 ap, at, ag, aq, am, ad, bp, bt, bg, bq, bm, bd;
    LOADSET(ap, at, ag, aq, am, ad, i0);             // A = iter 0
    LOADSET(bp, bt, bg, bq, bm, bd, i0 + 256);       // B = iter 1
    WAITSET(ap, at, ag, aq, am, ad, 6);
    proc(ap, at, ag, aq, am, ad);
    LOADSET(ap, at, ag, aq, am, ad, i0 + 512);       // A = iter 2
    WAITSET(bp, bt, bg, bq, bm, bd, 6);
    proc(bp, bt, bg, bq, bm, bd);
    LOADSET(bp, bt, bg, bq, bm, bd, i0 + 768);       // B = iter 3
    WAITSET(ap, at, ag, aq, am, ad, 6);
    proc(ap, at, ag, aq, am, ad);
    WAITSET(bp, bt, bg, bq, bm, bd, 0);
    proc(bp, bt, bg, bq, bm, bd);
    for (int off = 32; off; off >>= 1) {
        p1 += __shfl_down(p1, off, 64);
        p2 += __shfl_down(p2, off, 64);
        n1 += __shfl_down(n1, off, 64);
        n2 += __shfl_down(n2, off, 64);
        s3 += __shfl_down(s3, off, 64);
        s4 += __shfl_down(s4, off, 64);
        cp += __shfl_down(cp, off, 64);
        cn += __shfl_down(cn, off, 64);
    }
    if (!lane) {
        rf[wid][0] = p1; rf[wid][1] = p2; rf[wid][2] = n1;
        rf[wid][3] = n2; rf[wid][4] = s3; rf[wid][5] = s4;
        ri[wid][0] = cp; ri[wid][1] = cn;
    }
    __syncthreads();
    float* slice = part + (size_t)(n * SBPS + blockIdx.x) * SLW;
    int* slice_i = (int*)slice;
    if (t < NBIN) slice_i[t] = lc[t];
    if (!t) {
        slice_i[NBIN + 0] = ri[0][0] + ri[1][0] + ri[2][0] + ri[3][0];
        slice_i[NBIN + 1] = ri[0][1] + ri[1][1] + ri[2][1] + ri[3][1];
#pragma unroll
        for (int i = 0; i < 6; ++i)
            slice[NBIN + 2 + i] = rf[0][i] + rf[1][i] + rf[2][i] + rf[3][i];
    }
}

// ---------------- per-sample: reduce partials + select + suffix count -------
// modes: 0 = threshold in boundary bin; 1 = pos only; 2 = all masked; 3 = all neg+pos
__global__ void k_sel1(const float* __restrict__ part,
                       int* __restrict__ mode, int* __restrict__ b1o, int* __restrict__ k1o,
                       int* __restrict__ poss,
                       double* __restrict__ psum, double* __restrict__ abD, int* __restrict__ abc,
                       double* __restrict__ s3s, double* __restrict__ s4s) {
    __shared__ int lc[NBIN];
    __shared__ double sdr[4][6];
    __shared__ int sir[4][2];
    __shared__ int ric[4];
    __shared__ int sb1, sk1, s_md, s_k;
    const int n = blockIdx.x, t = threadIdx.x, lane = t & 63, wid = t >> 6;
    const float* base = part + (size_t)n * SBPS * SLW;
    double v[6] = {0, 0, 0, 0, 0, 0};
    int cp = 0, cn = 0;
    if (t < SBPS) {
        const float* sl = base + (size_t)t * SLW;
        const int* sli = (const int*)sl;
        cp = sli[NBIN + 0]; cn = sli[NBIN + 1];
#pragma unroll
        for (int i = 0; i < 6; ++i) v[i] = (double)sl[NBIN + 2 + i];
    }
    for (int off = 32; off; off >>= 1) {
#pragma unroll
        for (int i = 0; i < 6; ++i) v[i] += __shfl_down(v[i], off, 64);
        cp += __shfl_down(cp, off, 64);
        cn += __shfl_down(cn, off, 64);
    }
    if (!lane) {
#pragma unroll
        for (int i = 0; i < 6; ++i) sdr[wid][i] = v[i];
        sir[wid][0] = cp; sir[wid][1] = cn;
    }
    __syncthreads();
    if (!t) {
        int pos = sir[0][0] + sir[1][0] + sir[2][0] + sir[3][0];
        int neg = sir[0][1] + sir[1][1] + sir[2][1] + sir[3][1];
        double c[6];
#pragma unroll
        for (int i = 0; i < 6; ++i) c[i] = sdr[0][i] + sdr[1][i] + sdr[2][i] + sdr[3][i];
        int k = pos * 3; if (k > neg) k = neg;
        int md = (pos == 0) ? 2 : ((k == 0) ? 1 : ((k == neg) ? 3 : 0));
        mode[n] = md;
        poss[n] = pos;
        psum[n * 2 + 0] = c[0];     // pos bce1 sum
        psum[n * 2 + 1] = c[1];     // pos bce2 sum
        s3s[n] = c[4];
        s4s[n] = c[5];
        if (md == 1)      { abD[n * 16] = 0.0;  abD[n * 16 + 1] = 0.0;  abc[n] = 0; }
        else if (md != 0) { abD[n * 16] = c[2]; abD[n * 16 + 1] = c[3]; abc[n] = neg; }
        else              { abD[n * 16] = 0.0;  abD[n * 16 + 1] = 0.0; }  // gather fills
        s_md = md; s_k = k;
    }
    __syncthreads();
    if (s_md != 0) return;
    // ---- count-histogram reduction (2 thread-groups × 50 slices)
    if (t < NBIN) lc[t] = 0;
    __syncthreads();
    {
        const int bin = t & (NBIN - 1);
        const int j0 = (t < NBIN) ? 0 : SBPS / 2;
        const int j1 = (t < NBIN) ? SBPS / 2 : SBPS;
        int c = 0;
        for (int j = j0; j < j1; ++j) c += ((const int*)(base + (size_t)j * SLW))[bin];
        atomicAdd(&lc[bin], c);
    }
    __syncthreads();
    if (t < 64) { int b, r; if (wave_find(lc, NBIN, s_k, &b, &r)) { sb1 = b; sk1 = r; } }
    __syncthreads();
    const int B = sb1;
    if (!t) { b1o[n] = sb1; k1o[n] = sk1; }
    int ac = (t < NBIN && t > B) ? lc[t] : 0;
    for (int off = 32; off; off >>= 1) ac += __shfl_down(ac, off, 64);
    if (!lane) ric[wid] = ac;
    __syncthreads();
    if (!t) abc[n] = ric[0] + ric[1] + ric[2] + ric[3];
}

// ---------------- mode-0 gather: above-bin value sums + boundary candidates -
__global__ void k_gather(const float* __restrict__ outputs, const float* __restrict__ labels,
                         const float* __restrict__ tmask,
                         const int* __restrict__ mode, const int* __restrict__ b1a,
                         int* __restrict__ cand_cnt, unsigned* __restrict__ ck,
                         float* __restrict__ cv1, float* __restrict__ cv2,
                         double* __restrict__ abD) {
    const int n = blockIdx.y;
    if (mode[n] != 0) return;   // modes 1/2/3 fully resolved in sel1
    const int b1n = b1a[n];
    __shared__ int lcnt, lbase;
    __shared__ unsigned lsk[BCAP];
    __shared__ float lv1[BCAP], lv2[BCAP];
    __shared__ double rdd[4][2];
    const int t = threadIdx.x, lane = t & 63, wid = t >> 6;
    if (!t) lcnt = 0;
    __syncthreads();
    const float* bp = outputs + (size_t)n * 2 * HWSZ;
    const float4* P  = (const float4*)bp;
    const float4* Th = P + NF4;
    const float4* G  = (const float4*)(labels + (size_t)n * 2 * HWSZ);
    const float4* T  = (const float4*)(tmask + (size_t)n * HWSZ);
    const int stride = GBPS * 256;
    float a1 = 0.f, a2 = 0.f;
    for (int i4 = blockIdx.x * 256 + t; i4 < NF4; i4 += stride) {
        float4 p = P[i4], th = Th[i4], g = G[i4], m = T[i4];
        const float* pp = (const float*)&p;  const float* tt = (const float*)&th;
        const float* gg = (const float*)&g;  const float* mm = (const float*)&m;
#pragma unroll
        for (int e = 0; e < 4; ++e) {
            bool neg = (gg[e] <= 0.5f) && (mm[e] > 0.5f);
            int bin = pbin(pp[e]);
            if (neg && bin >= b1n) {
                float o1, o2; bce_pair(pp[e], tt[e], false, o1, o2);
                if (bin > b1n) { a1 += o1; a2 += o2; }
                else {
                    int idx = atomicAdd(&lcnt, 1);
                    if (idx < BCAP) { lsk[idx] = fkey(pp[e]); lv1[idx] = o1; lv2[idx] = o2; }
                    else {
                        int gi = atomicAdd(&cand_cnt[n * PADI], 1);   // rare overflow
                        if (gi < CAP) { ck[n * CAP + gi] = fkey(pp[e]); cv1[n * CAP + gi] = o1; cv2[n * CAP + gi] = o2; }
                    }
                }
            }
        }
    }
    double v0 = a1, v1 = a2;
    for (int off = 32; off; off >>= 1) {
        v0 += __shfl_down(v0, off, 64);
        v1 += __shfl_down(v1, off, 64);
    }
    if (!lane) { rdd[wid][0] = v0; rdd[wid][1] = v1; }
    __syncthreads();
    if (!t) {
        double sA = rdd[0][0] + rdd[1][0] + rdd[2][0] + rdd[3][0];
        double sB = rdd[0][1] + rdd[1][1] + rdd[2][1] + rdd[3][1];
        if (sA != 0.0) atomicAdd(&abD[n * 16], sA);
        if (sB != 0.0) atomicAdd(&abD[n * 16 + 1], sB);
    }
    __syncthreads();
    const int cnt = min(lcnt, BCAP);
    if (!t && cnt) lbase = atomicAdd(&cand_cnt[n * PADI], cnt);
    __syncthreads();
    if (cnt) {
        const int bb = lbase;
        for (int i = t; i < cnt; i += 256) {
            int gi = bb + i;
            if (gi < CAP) { ck[n * CAP + gi] = lsk[i]; cv1[n * CAP + gi] = lv1[i]; cv2[n * CAP + gi] = lv2[i]; }
        }
    }
}

// ---------------- per-sample finalize (plain stores) ------------------------
__global__ void k_final(const float* __restrict__ outputs, const float* __restrict__ labels,
                        const float* __restrict__ tmask,
                        const int* __restrict__ mode, const int* __restrict__ b1a,
                        const int* __restrict__ k1a, const int* __restrict__ poss,
                        const int* __restrict__ cand_cnt, const unsigned* __restrict__ ck,
                        const float* __restrict__ cv1, const float* __restrict__ cv2,
                        const double* __restrict__ psum, const double* __restrict__ abD,
                        const int* __restrict__ abc, double* __restrict__ res) {
    __shared__ unsigned sk[CAP];
    __shared__ float sv1[CAP], sv2[CAP];
    __shared__ int h[2048];
    __shared__ int sbh, srh, sbm, srm, sbl;
    __shared__ double rd[4][2];
    __shared__ int ri[4];
    const int n = blockIdx.x, t = threadIdx.x;
    const int md = mode[n];
    double f1r = 0.0, f2r = 0.0; int fcr = 0;
    if (md == 0) {
        const int k1 = k1a[n];
        const int cc = cand_cnt[n * PADI];
        float f1 = 0.f, f2 = 0.f; int fc = 0;
        if (cc <= CAP) {
            for (int i = t; i < cc; i += 256) {
                sk[i] = ck[n * CAP + i]; sv1[i] = cv1[n * CAP + i]; sv2[i] = cv2[n * CAP + i];
            }
            for (int i = t; i < 2048; i += 256) h[i] = 0;
            __syncthreads();
            for (int i = t; i < cc; i += 256) atomicAdd(&h[sk[i] >> 21], 1);
            __syncthreads();
            if (t < 64) { int b, r; if (wave_find(h, 2048, k1, &b, &r)) { sbh = b; srh = r; } }
            __syncthreads();
            const unsigned bh = (unsigned)sbh; const int r2 = srh;
            for (int i = t; i < 2048; i += 256) h[i] = 0;
            __syncthreads();
            for (int i = t; i < cc; i += 256)
                if ((sk[i] >> 21) == bh) atomicAdd(&h[(sk[i] >> 10) & 0x7FFu], 1);
            __syncthreads();
            if (t < 64) { int b, r; if (wave_find(h, 2048, r2, &b, &r)) { sbm = b; srm = r; } }
            __syncthreads();
            const unsigned bm = (unsigned)sbm; const int r3 = srm;
            for (int i = t; i < 1024; i += 256) h[i] = 0;
            __syncthreads();
            for (int i = t; i < cc; i += 256)
                if ((sk[i] >> 10) == ((bh << 11) | bm)) atomicAdd(&h[sk[i] & 0x3FFu], 1);
            __syncthreads();
            if (t < 64) { int b, r; if (wave_find(h, 1024, r3, &b, &r)) sbl = b; }
            __syncthreads();
            const unsigned thr_key = (bh << 21) | (bm << 10) | (unsigned)sbl;
            for (int i = t; i < cc; i += 256)
                if (sk[i] >= thr_key) { f1 += sv1[i]; f2 += sv2[i]; fc++; }
        } else {
            // slow path: rescan boundary bin from global (general insurance)
            const int b1n = b1a[n];
            const float* Pp = outputs + (size_t)n * 2 * HWSZ;
            const float* Thp = Pp + HWSZ;
            const float* Gp = labels + (size_t)n * 2 * HWSZ;
            const float* Tp = tmask + (size_t)n * HWSZ;
            for (int i = t; i < 2048; i += 256) h[i] = 0;
            __syncthreads();
            for (int i = t; i < HWSZ; i += 256) {
                float pv = Pp[i];
                if (Gp[i] <= 0.5f && Tp[i] > 0.5f && pbin(pv) == b1n)
                    atomicAdd(&h[fkey(pv) >> 21], 1);
            }
            __syncthreads();
            if (t < 64) { int b, r; if (wave_find(h, 2048, k1, &b, &r)) { sbh = b; srh = r; } }
            __syncthreads();
            const unsigned bh = (unsigned)sbh; const int r2 = srh;
            for (int i = t; i < 2048; i += 256) h[i] = 0;
            __syncthreads();
            for (int i = t; i < HWSZ; i += 256) {
                float pv = Pp[i]; unsigned key = fkey(pv);
                if (Gp[i] <= 0.5f && Tp[i] > 0.5f && pbin(pv) == b1n && (key >> 21) == bh)
                    atomicAdd(&h[(key >> 10) & 0x7FFu], 1);
            }
            __syncthreads();
            if (t < 64) { int b, r; if (wave_find(h, 2048, r2, &b, &r)) { sbm = b; srm = r; } }
            __syncthreads();
            const unsigned bm = (unsigned)sbm; const int r3 = srm;
            for (int i = t; i < 1024; i += 256) h[i] = 0;
            __syncthreads();
            for (int i = t; i < HWSZ; i += 256) {
                float pv = Pp[i]; unsigned key = fkey(pv);
                if (Gp[i] <= 0.5f && Tp[i] > 0.5f && pbin(pv) == b1n && (key >> 10) == ((bh << 11) | bm))
                    atomicAdd(&h[key & 0x3FFu], 1);
            }
            __syncthreads();
            if (t < 64) { int b, r; if (wave_find(h, 1024, r3, &b, &r)) sbl = b; }
            __syncthreads();
            const unsigned thr_key = (bh << 21) | (bm << 10) | (unsigned)sbl;
            for (int i = t; i < HWSZ; i += 256) {
                float pv = Pp[i];
                if (Gp[i] <= 0.5f && Tp[i] > 0.5f && pbin(pv) == b1n && fkey(pv) >= thr_key) {
                    float b1v, b2v; bce_pair(pv, Thp[i], false, b1v, b2v);
                    f1 += b1v; f2 += b2v; fc++;
                }
            }
        }
        double v0 = f1, v1 = f2;
        for (int off = 32; off; off >>= 1) {
            v0 += __shfl_down(v0, off, 64);
            v1 += __shfl_down(v1, off, 64);
            fc += __shfl_down(fc, off, 64);
        }
        const int lane = t & 63, wid = t >> 6;
        if (!lane) { rd[wid][0] = v0; rd[wid][1] = v1; ri[wid] = fc; }
        __syncthreads();
        if (!t) {
            f1r = rd[0][0] + rd[1][0] + rd[2][0] + rd[3][0];
            f2r = rd[0][1] + rd[1][1] + rd[2][1] + rd[3][1];
            fcr = ri[0] + ri[1] + ri[2] + ri[3];
        }
    }
    if (!t) {
        res[n * 3 + 0] = psum[n * 2 + 0] + abD[n * 16] + f1r;
        res[n * 3 + 1] = psum[n * 2 + 1] + abD[n * 16 + 1] + f2r;
        res[n * 3 + 2] = (double)poss[n] + (double)abc[n] + (double)fcr;
    }
}

__global__ void k_fin(const double* __restrict__ res, const double* __restrict__ s3s,
                      const double* __restrict__ s4s, float* __restrict__ out) {
    if (threadIdx.x != 0 || blockIdx.x != 0) return;
    double A = 0.0, Bb = 0.0, C = 0.0, S3 = 0.0, S4 = 0.0;
    for (int n = 0; n < NS; ++n) {
        A += res[n * 3 + 0]; Bb += res[n * 3 + 1]; C += res[n * 3 + 2];
        S3 += s3s[n]; S4 += s4s[n];
    }
    double lp = (C > 0.0) ? A / C : 0.0;
    double lb = (C > 0.0) ? Bb / C : 0.0;
    double lt = S3 / (S4 + 1e-6);
    out[0] = (float)(lp + lb + 10.0 * lt);
    out[1] = (float)lp;
    out[2] = (float)lb;
    out[3] = (float)lt;
}

extern "C" void kernel_launch(void* const* d_in, const int* in_sizes, int n_in,
                              void* d_out, int out_size, void* d_ws, size_t ws_size,
                              hipStream_t stream) {
    const float* outputs = (const float*)d_in[0];
    const float* labels  = (const float*)d_in[1];
    const float* tmask   = (const float*)d_in[2];
    const float* gd      = (const float*)d_in[3];
    float* out = (float*)d_out;

    char* ws = (char*)d_ws;
    double* s3s   = (double*)ws;                 // NS
    double* s4s   = s3s + NS;                    // NS
    double* psum  = s4s + NS;                    // NS*2
    double* abD   = psum + NS * 2;               // NS*16 (padded: [n*16]=ab1,[n*16+1]=ab2)
    double* res   = abD + NS * 16;               // NS*3
    int* abc      = (int*)(res + NS * 3);        // NS
    int* mode     = abc + NS;                    // NS
    int* b1       = mode + NS;                   // NS
    int* k1       = b1 + NS;                     // NS
    int* poss     = k1 + NS;                     // NS
    int* cand_cnt = poss + NS;                   // NS*PADI (padded counters)
    float* part   = (float*)(cand_cnt + NS * PADI);  // NS*SBPS*SLW (fully written)
    unsigned* ck  = (unsigned*)(part + (size_t)NS * SBPS * SLW);  // NS*CAP
    float* cv1    = (float*)(ck + NS * CAP);
    float* cv2    = cv1 + NS * CAP;
    (void)cv2; (void)ws_size; (void)in_sizes; (void)n_in; (void)out_size;

    // only the padded counters need zeroing; everything else is overwritten
    hipMemsetAsync(cand_cnt, 0, NS * PADI * sizeof(int), stream);

    k_scan1<<<dim3(SBPS, NS), 256, 0, stream>>>(outputs, labels, tmask, gd, part);
    k_sel1<<<NS, 256, 0, stream>>>(part, mode, b1, k1, poss, psum, abD, abc, s3s, s4s);
    k_gather<<<dim3(GBPS, NS), 256, 0, stream>>>(outputs, labels, tmask, mode, b1,
                                                 cand_cnt, ck, cv1, cv2, abD);
    k_final<<<NS, 256, 0, stream>>>(outputs, labels, tmask, mode, b1, k1, poss, cand_cnt,
                                    ck, cv1, cv2, psum, abD, abc, res);
    k_fin<<<1, 64, 0, stream>>>(res, s3s, s4s, out);
}

// Round 13
// 39.027 us; speedup vs baseline: 1.5395x; 1.1456x over previous
//
#include <hip/hip_runtime.h>
#include <math.h>
#include <stdint.h>

#define NS    16
#define HWSZ  409600
#define NF4   102400      // float4s per sample
#define NBIN  128
#define SLW   (NBIN + 8)  // slice: count hist + 8 scalars (cp,cn,p1,p2,n1,n2,s3,s4)
#define CAP   4096
#define BCAP  512         // per-block LDS candidate staging
#define SBPS  100         // scan blocks per sample (4 pipelined iters of 256 f4)
#define GBPS  100         // gather blocks per sample
#define PADI  32          // ints per sample for padded atomic counter (128 B)

typedef unsigned long long u64;
typedef float f32x4 __attribute__((ext_vector_type(4)));

__device__ __forceinline__ unsigned fkey(float f) {
    unsigned u = __float_as_uint(f);
    if (u == 0x80000000u) u = 0u;                 // canonicalize -0
    return (u & 0x80000000u) ? ~u : (u | 0x80000000u);
}

// bce1: BCE on p; bce2: BCE on sigmoid(50(p-t)); both with 1e-7 clipping
__device__ __forceinline__ void bce_pair(float pv, float tv, bool tc, float& o1, float& o2) {
    float pc = fminf(fmaxf(pv, 1e-7f), 1.0f - 1e-7f);
    float a = tc ? pc : 1.0f - pc;
    o1 = -__logf(a);
    float x = 50.0f * (pv - tv);
    float y = tc ? -x : x;
    float t2 = __expf(-fabsf(y));
    float sp = __logf(1.0f + t2);
    sp = (y > 0.0f) ? y + sp : sp;
    o2 = fminf(sp, 16.118095651f);
}

__device__ __forceinline__ int pbin(float p) {
    int b = (int)(p * (float)NBIN);
    return min(max(b, 0), NBIN - 1);
}

// Wave-parallel descending k-th-largest bin search over a histogram.
__device__ __forceinline__ bool wave_find(const int* __restrict__ h, int nbins, int k,
                                          int* bin_out, int* rank_out) {
    const int lane = threadIdx.x & 63;
    const int CH = nbins >> 6;
    const int topStart = nbins - 1 - lane * CH;
    int s = 0;
    for (int b = 0; b < CH; ++b) s += h[topStart - b];
    int incl = s;
    for (int off = 1; off < 64; off <<= 1) {
        int v = __shfl_up(incl, off, 64);
        if (lane >= off) incl += v;
    }
    int before = incl - s;
    if (before < k && k <= incl) {
        int c = before;
        for (int b = 0; b < CH; ++b) {
            int hb = h[topStart - b];
            c += hb;
            if (c >= k) { *bin_out = topStart - b; *rank_out = k - (c - hb); return true; }
        }
    }
    return false;
}

#define GLOAD(dst, addr) \
    asm volatile("global_load_dwordx4 %0, %1, off" : "=v"(dst) : "v"(addr))
#define LOADSET(Sp, St, Sg, Sq, Sm, Sd, idx) do { \
    GLOAD(Sp, P + (idx));  GLOAD(St, Th + (idx)); GLOAD(Sg, G + (idx)); \
    GLOAD(Sq, Gt + (idx)); GLOAD(Sm, T + (idx)); GLOAD(Sd, D + (idx)); } while (0)
#define WAITSET(Sp, St, Sg, Sq, Sm, Sd, N) \
    asm volatile("s_waitcnt vmcnt(" #N ")" \
                 : "+v"(Sp), "+v"(St), "+v"(Sg), "+v"(Sq), "+v"(Sm), "+v"(Sd))

// ---------------- fat pass: 3-deep pipelined streaming ----------------------
__global__ void k_scan1(const float* __restrict__ outputs, const float* __restrict__ labels,
                        const float* __restrict__ tmask, const float* __restrict__ gd,
                        float* __restrict__ part) {
    __shared__ int lc[NBIN];
    __shared__ float rf[4][6];
    __shared__ int ri[4][2];
    const int t = threadIdx.x, n = blockIdx.y, lane = t & 63, wid = t >> 6;
    if (t < NBIN) lc[t] = 0;
    __syncthreads();
    const f32x4* P  = (const f32x4*)(outputs + (size_t)n * 2 * HWSZ);
    const f32x4* Th = P + NF4;
    const f32x4* G  = (const f32x4*)(labels + (size_t)n * 2 * HWSZ);
    const f32x4* Gt = G + NF4;
    const f32x4* T  = (const f32x4*)(tmask + (size_t)n * HWSZ);
    const f32x4* D  = (const f32x4*)(gd + (size_t)n * HWSZ);
    const int i0 = blockIdx.x * 1024 + t;         // 4 iterations, stride 256
    float s3 = 0.f, s4 = 0.f, p1 = 0.f, p2 = 0.f, n1 = 0.f, n2 = 0.f;
    int cp = 0, cn = 0;
    auto proc = [&](const f32x4& p, const f32x4& th, const f32x4& g, const f32x4& q,
                    const f32x4& m, const f32x4& d) {
#pragma unroll
        for (int e = 0; e < 4; ++e) {
            float pv = p[e], tv = th[e], gv = g[e], qv = q[e], mv = m[e], dv = d[e];
            s3 += fabsf(tv - qv) * dv;
            s4 += dv;
            bool msk = mv > 0.5f, tc = gv > 0.5f;
            if (msk) {
                float o1, o2; bce_pair(pv, tv, tc, o1, o2);
                if (tc) { p1 += o1; p2 += o2; cp++; }
                else    { n1 += o1; n2 += o2; cn++; atomicAdd(&lc[pbin(pv)], 1); }
            }
        }
    };
    f32x4 ap, at, ag, aq, am, ad, bp, bt, bg, bq, bm, bd, cq, ct, cg, cqq, cm, cd;
    // 3-deep: 18 loads in flight; counted waits keep >=6 outstanding mid-stream
    LOADSET(ap, at, ag, aq, am, ad, i0);              // set A = iter 0
    LOADSET(bp, bt, bg, bq, bm, bd, i0 + 256);        // set B = iter 1
    LOADSET(cq, ct, cg, cqq, cm, cd, i0 + 512);       // set C = iter 2
    WAITSET(ap, at, ag, aq, am, ad, 12);
    proc(ap, at, ag, aq, am, ad);
    LOADSET(ap, at, ag, aq, am, ad, i0 + 768);        // set A = iter 3
    WAITSET(bp, bt, bg, bq, bm, bd, 12);
    proc(bp, bt, bg, bq, bm, bd);
    WAITSET(cq, ct, cg, cqq, cm, cd, 6);
    proc(cq, ct, cg, cqq, cm, cd);
    WAITSET(ap, at, ag, aq, am, ad, 0);
    proc(ap, at, ag, aq, am, ad);
    for (int off = 32; off; off >>= 1) {
        p1 += __shfl_down(p1, off, 64);
        p2 += __shfl_down(p2, off, 64);
        n1 += __shfl_down(n1, off, 64);
        n2 += __shfl_down(n2, off, 64);
        s3 += __shfl_down(s3, off, 64);
        s4 += __shfl_down(s4, off, 64);
        cp += __shfl_down(cp, off, 64);
        cn += __shfl_down(cn, off, 64);
    }
    if (!lane) {
        rf[wid][0] = p1; rf[wid][1] = p2; rf[wid][2] = n1;
        rf[wid][3] = n2; rf[wid][4] = s3; rf[wid][5] = s4;
        ri[wid][0] = cp; ri[wid][1] = cn;
    }
    __syncthreads();
    float* slice = part + (size_t)(n * SBPS + blockIdx.x) * SLW;
    int* slice_i = (int*)slice;
    if (t < NBIN) slice_i[t] = lc[t];
    if (!t) {
        slice_i[NBIN + 0] = ri[0][0] + ri[1][0] + ri[2][0] + ri[3][0];
        slice_i[NBIN + 1] = ri[0][1] + ri[1][1] + ri[2][1] + ri[3][1];
#pragma unroll
        for (int i = 0; i < 6; ++i)
            slice[NBIN + 2 + i] = rf[0][i] + rf[1][i] + rf[2][i] + rf[3][i];
    }
}

// ---------------- per-sample: reduce partials + select + suffix count -------
// modes: 0 = threshold in boundary bin; 1 = pos only; 2 = all masked; 3 = all neg+pos
__global__ void k_sel1(const float* __restrict__ part,
                       int* __restrict__ mode, int* __restrict__ b1o, int* __restrict__ k1o,
                       int* __restrict__ poss,
                       double* __restrict__ psum, double* __restrict__ abD, int* __restrict__ abc,
                       double* __restrict__ s3s, double* __restrict__ s4s,
                       int* __restrict__ cand_cnt, unsigned* __restrict__ done) {
    __shared__ int lc[NBIN];
    __shared__ double sdr[4][6];
    __shared__ int sir[4][2];
    __shared__ int ric[4];
    __shared__ int sb1, sk1, s_md, s_k;
    const int n = blockIdx.x, t = threadIdx.x, lane = t & 63, wid = t >> 6;
    // zero the per-call mutable state (replaces host-side memset)
    if (t < PADI) cand_cnt[n * PADI + t] = 0;
    if (!n && !t) *done = 0u;
    const float* base = part + (size_t)n * SBPS * SLW;
    double v[6] = {0, 0, 0, 0, 0, 0};
    int cp = 0, cn = 0;
    if (t < SBPS) {
        const float* sl = base + (size_t)t * SLW;
        const int* sli = (const int*)sl;
        cp = sli[NBIN + 0]; cn = sli[NBIN + 1];
#pragma unroll
        for (int i = 0; i < 6; ++i) v[i] = (double)sl[NBIN + 2 + i];
    }
    for (int off = 32; off; off >>= 1) {
#pragma unroll
        for (int i = 0; i < 6; ++i) v[i] += __shfl_down(v[i], off, 64);
        cp += __shfl_down(cp, off, 64);
        cn += __shfl_down(cn, off, 64);
    }
    if (!lane) {
#pragma unroll
        for (int i = 0; i < 6; ++i) sdr[wid][i] = v[i];
        sir[wid][0] = cp; sir[wid][1] = cn;
    }
    __syncthreads();
    if (!t) {
        int pos = sir[0][0] + sir[1][0] + sir[2][0] + sir[3][0];
        int neg = sir[0][1] + sir[1][1] + sir[2][1] + sir[3][1];
        double c[6];
#pragma unroll
        for (int i = 0; i < 6; ++i) c[i] = sdr[0][i] + sdr[1][i] + sdr[2][i] + sdr[3][i];
        int k = pos * 3; if (k > neg) k = neg;
        int md = (pos == 0) ? 2 : ((k == 0) ? 1 : ((k == neg) ? 3 : 0));
        mode[n] = md;
        poss[n] = pos;
        psum[n * 2 + 0] = c[0];     // pos bce1 sum
        psum[n * 2 + 1] = c[1];     // pos bce2 sum
        s3s[n] = c[4];
        s4s[n] = c[5];
        if (md == 1)      { abD[n * 16] = 0.0;  abD[n * 16 + 1] = 0.0;  abc[n] = 0; }
        else if (md != 0) { abD[n * 16] = c[2]; abD[n * 16 + 1] = c[3]; abc[n] = neg; }
        else              { abD[n * 16] = 0.0;  abD[n * 16 + 1] = 0.0; }  // gather fills
        s_md = md; s_k = k;
    }
    __syncthreads();
    if (s_md != 0) return;
    // ---- count-histogram reduction (2 thread-groups × 50 slices)
    if (t < NBIN) lc[t] = 0;
    __syncthreads();
    {
        const int bin = t & (NBIN - 1);
        const int j0 = (t < NBIN) ? 0 : SBPS / 2;
        const int j1 = (t < NBIN) ? SBPS / 2 : SBPS;
        int c = 0;
        for (int j = j0; j < j1; ++j) c += ((const int*)(base + (size_t)j * SLW))[bin];
        atomicAdd(&lc[bin], c);
    }
    __syncthreads();
    if (t < 64) { int b, r; if (wave_find(lc, NBIN, s_k, &b, &r)) { sb1 = b; sk1 = r; } }
    __syncthreads();
    const int B = sb1;
    if (!t) { b1o[n] = sb1; k1o[n] = sk1; }
    int ac = (t < NBIN && t > B) ? lc[t] : 0;
    for (int off = 32; off; off >>= 1) ac += __shfl_down(ac, off, 64);
    if (!lane) ric[wid] = ac;
    __syncthreads();
    if (!t) abc[n] = ric[0] + ric[1] + ric[2] + ric[3];
}

// ---------------- mode-0 gather: above-bin value sums + boundary candidates -
__global__ void k_gather(const float* __restrict__ outputs, const float* __restrict__ labels,
                         const float* __restrict__ tmask,
                         const int* __restrict__ mode, const int* __restrict__ b1a,
                         int* __restrict__ cand_cnt, unsigned* __restrict__ ck,
                         float* __restrict__ cv1, float* __restrict__ cv2,
                         double* __restrict__ abD) {
    const int n = blockIdx.y;
    if (mode[n] != 0) return;   // modes 1/2/3 fully resolved in sel1
    const int b1n = b1a[n];
    __shared__ int lcnt, lbase;
    __shared__ unsigned lsk[BCAP];
    __shared__ float lv1[BCAP], lv2[BCAP];
    __shared__ double rdd[4][2];
    const int t = threadIdx.x, lane = t & 63, wid = t >> 6;
    if (!t) lcnt = 0;
    __syncthreads();
    const float* bp = outputs + (size_t)n * 2 * HWSZ;
    const float4* P  = (const float4*)bp;
    const float4* Th = P + NF4;
    const float4* G  = (const float4*)(labels + (size_t)n * 2 * HWSZ);
    const float4* T  = (const float4*)(tmask + (size_t)n * HWSZ);
    const int stride = GBPS * 256;
    float a1 = 0.f, a2 = 0.f;
    for (int i4 = blockIdx.x * 256 + t; i4 < NF4; i4 += stride) {
        float4 p = P[i4], th = Th[i4], g = G[i4], m = T[i4];
        const float* pp = (const float*)&p;  const float* tt = (const float*)&th;
        const float* gg = (const float*)&g;  const float* mm = (const float*)&m;
#pragma unroll
        for (int e = 0; e < 4; ++e) {
            bool neg = (gg[e] <= 0.5f) && (mm[e] > 0.5f);
            int bin = pbin(pp[e]);
            if (neg && bin >= b1n) {
                float o1, o2; bce_pair(pp[e], tt[e], false, o1, o2);
                if (bin > b1n) { a1 += o1; a2 += o2; }
                else {
                    int idx = atomicAdd(&lcnt, 1);
                    if (idx < BCAP) { lsk[idx] = fkey(pp[e]); lv1[idx] = o1; lv2[idx] = o2; }
                    else {
                        int gi = atomicAdd(&cand_cnt[n * PADI], 1);   // rare overflow
                        if (gi < CAP) { ck[n * CAP + gi] = fkey(pp[e]); cv1[n * CAP + gi] = o1; cv2[n * CAP + gi] = o2; }
                    }
                }
            }
        }
    }
    double v0 = a1, v1 = a2;
    for (int off = 32; off; off >>= 1) {
        v0 += __shfl_down(v0, off, 64);
        v1 += __shfl_down(v1, off, 64);
    }
    if (!lane) { rdd[wid][0] = v0; rdd[wid][1] = v1; }
    __syncthreads();
    if (!t) {
        double sA = rdd[0][0] + rdd[1][0] + rdd[2][0] + rdd[3][0];
        double sB = rdd[0][1] + rdd[1][1] + rdd[2][1] + rdd[3][1];
        if (sA != 0.0) atomicAdd(&abD[n * 16], sA);
        if (sB != 0.0) atomicAdd(&abD[n * 16 + 1], sB);
    }
    __syncthreads();
    const int cnt = min(lcnt, BCAP);
    if (!t && cnt) lbase = atomicAdd(&cand_cnt[n * PADI], cnt);
    __syncthreads();
    if (cnt) {
        const int bb = lbase;
        for (int i = t; i < cnt; i += 256) {
            int gi = bb + i;
            if (gi < CAP) { ck[n * CAP + gi] = lsk[i]; cv1[n * CAP + gi] = lv1[i]; cv2[n * CAP + gi] = lv2[i]; }
        }
    }
}

// ---------------- per-sample finalize + fused global reduction --------------
__global__ void k_final(const float* __restrict__ outputs, const float* __restrict__ labels,
                        const float* __restrict__ tmask,
                        const int* __restrict__ mode, const int* __restrict__ b1a,
                        const int* __restrict__ k1a, const int* __restrict__ poss,
                        const int* __restrict__ cand_cnt, const unsigned* __restrict__ ck,
                        const float* __restrict__ cv1, const float* __restrict__ cv2,
                        const double* __restrict__ psum, const double* __restrict__ abD,
                        const int* __restrict__ abc, double* __restrict__ res,
                        const double* __restrict__ s3s, const double* __restrict__ s4s,
                        unsigned* __restrict__ done, float* __restrict__ out) {
    __shared__ unsigned sk[CAP];
    __shared__ float sv1[CAP], sv2[CAP];
    __shared__ int h[2048];
    __shared__ int sbh, srh, sbm, srm, sbl;
    __shared__ double rd[4][2];
    __shared__ int ri[4];
    const int n = blockIdx.x, t = threadIdx.x;
    const int md = mode[n];
    double f1r = 0.0, f2r = 0.0; int fcr = 0;
    if (md == 0) {
        const int k1 = k1a[n];
        const int cc = cand_cnt[n * PADI];
        float f1 = 0.f, f2 = 0.f; int fc = 0;
        if (cc <= CAP) {
            for (int i = t; i < cc; i += 256) {
                sk[i] = ck[n * CAP + i]; sv1[i] = cv1[n * CAP + i]; sv2[i] = cv2[n * CAP + i];
            }
            for (int i = t; i < 2048; i += 256) h[i] = 0;
            __syncthreads();
            for (int i = t; i < cc; i += 256) atomicAdd(&h[sk[i] >> 21], 1);
            __syncthreads();
            if (t < 64) { int b, r; if (wave_find(h, 2048, k1, &b, &r)) { sbh = b; srh = r; } }
            __syncthreads();
            const unsigned bh = (unsigned)sbh; const int r2 = srh;
            for (int i = t; i < 2048; i += 256) h[i] = 0;
            __syncthreads();
            for (int i = t; i < cc; i += 256)
                if ((sk[i] >> 21) == bh) atomicAdd(&h[(sk[i] >> 10) & 0x7FFu], 1);
            __syncthreads();
            if (t < 64) { int b, r; if (wave_find(h, 2048, r2, &b, &r)) { sbm = b; srm = r; } }
            __syncthreads();
            const unsigned bm = (unsigned)sbm; const int r3 = srm;
            for (int i = t; i < 1024; i += 256) h[i] = 0;
            __syncthreads();
            for (int i = t; i < cc; i += 256)
                if ((sk[i] >> 10) == ((bh << 11) | bm)) atomicAdd(&h[sk[i] & 0x3FFu], 1);
            __syncthreads();
            if (t < 64) { int b, r; if (wave_find(h, 1024, r3, &b, &r)) sbl = b; }
            __syncthreads();
            const unsigned thr_key = (bh << 21) | (bm << 10) | (unsigned)sbl;
            for (int i = t; i < cc; i += 256)
                if (sk[i] >= thr_key) { f1 += sv1[i]; f2 += sv2[i]; fc++; }
        } else {
            // slow path: rescan boundary bin from global (general insurance)
            const int b1n = b1a[n];
            const float* Pp = outputs + (size_t)n * 2 * HWSZ;
            const float* Thp = Pp + HWSZ;
            const float* Gp = labels + (size_t)n * 2 * HWSZ;
            const float* Tp = tmask + (size_t)n * HWSZ;
            for (int i = t; i < 2048; i += 256) h[i] = 0;
            __syncthreads();
            for (int i = t; i < HWSZ; i += 256) {
                float pv = Pp[i];
                if (Gp[i] <= 0.5f && Tp[i] > 0.5f && pbin(pv) == b1n)
                    atomicAdd(&h[fkey(pv) >> 21], 1);
            }
            __syncthreads();
            if (t < 64) { int b, r; if (wave_find(h, 2048, k1, &b, &r)) { sbh = b; srh = r; } }
            __syncthreads();
            const unsigned bh = (unsigned)sbh; const int r2 = srh;
            for (int i = t; i < 2048; i += 256) h[i] = 0;
            __syncthreads();
            for (int i = t; i < HWSZ; i += 256) {
                float pv = Pp[i]; unsigned key = fkey(pv);
                if (Gp[i] <= 0.5f && Tp[i] > 0.5f && pbin(pv) == b1n && (key >> 21) == bh)
                    atomicAdd(&h[(key >> 10) & 0x7FFu], 1);
            }
            __syncthreads();
            if (t < 64) { int b, r; if (wave_find(h, 2048, r2, &b, &r)) { sbm = b; srm = r; } }
            __syncthreads();
            const unsigned bm = (unsigned)sbm; const int r3 = srm;
            for (int i = t; i < 1024; i += 256) h[i] = 0;
            __syncthreads();
            for (int i = t; i < HWSZ; i += 256) {
                float pv = Pp[i]; unsigned key = fkey(pv);
                if (Gp[i] <= 0.5f && Tp[i] > 0.5f && pbin(pv) == b1n && (key >> 10) == ((bh << 11) | bm))
                    atomicAdd(&h[key & 0x3FFu], 1);
            }
            __syncthreads();
            if (t < 64) { int b, r; if (wave_find(h, 1024, r3, &b, &r)) sbl = b; }
            __syncthreads();
            const unsigned thr_key = (bh << 21) | (bm << 10) | (unsigned)sbl;
            for (int i = t; i < HWSZ; i += 256) {
                float pv = Pp[i];
                if (Gp[i] <= 0.5f && Tp[i] > 0.5f && pbin(pv) == b1n && fkey(pv) >= thr_key) {
                    float b1v, b2v; bce_pair(pv, Thp[i], false, b1v, b2v);
                    f1 += b1v; f2 += b2v; fc++;
                }
            }
        }
        double v0 = f1, v1 = f2;
        for (int off = 32; off; off >>= 1) {
            v0 += __shfl_down(v0, off, 64);
            v1 += __shfl_down(v1, off, 64);
            fc += __shfl_down(fc, off, 64);
        }
        const int lane = t & 63, wid = t >> 6;
        if (!lane) { rd[wid][0] = v0; rd[wid][1] = v1; ri[wid] = fc; }
        __syncthreads();
        if (!t) {
            f1r = rd[0][0] + rd[1][0] + rd[2][0] + rd[3][0];
            f2r = rd[0][1] + rd[1][1] + rd[2][1] + rd[3][1];
            fcr = ri[0] + ri[1] + ri[2] + ri[3];
        }
    }
    if (!t) {
        res[n * 3 + 0] = psum[n * 2 + 0] + abD[n * 16] + f1r;
        res[n * 3 + 1] = psum[n * 2 + 1] + abD[n * 16 + 1] + f2r;
        res[n * 3 + 2] = (double)poss[n] + (double)abc[n] + (double)fcr;
        __threadfence();                                   // publish res before signaling
        unsigned v = atomicAdd(done, 1u);
        if (v == NS - 1) {                                 // last block: fused k_fin
            __threadfence();                               // acquire all res stores
            double A = 0.0, Bb = 0.0, C = 0.0, S3 = 0.0, S4 = 0.0;
            for (int m = 0; m < NS; ++m) {
                A += res[m * 3 + 0]; Bb += res[m * 3 + 1]; C += res[m * 3 + 2];
                S3 += s3s[m]; S4 += s4s[m];
            }
            double lp = (C > 0.0) ? A / C : 0.0;
            double lb = (C > 0.0) ? Bb / C : 0.0;
            double lt = S3 / (S4 + 1e-6);
            out[0] = (float)(lp + lb + 10.0 * lt);
            out[1] = (float)lp;
            out[2] = (float)lb;
            out[3] = (float)lt;
        }
    }
}

extern "C" void kernel_launch(void* const* d_in, const int* in_sizes, int n_in,
                              void* d_out, int out_size, void* d_ws, size_t ws_size,
                              hipStream_t stream) {
    const float* outputs = (const float*)d_in[0];
    const float* labels  = (const float*)d_in[1];
    const float* tmask   = (const float*)d_in[2];
    const float* gd      = (const float*)d_in[3];
    float* out = (float*)d_out;

    char* ws = (char*)d_ws;
    double* s3s   = (double*)ws;                 // NS
    double* s4s   = s3s + NS;                    // NS
    double* psum  = s4s + NS;                    // NS*2
    double* abD   = psum + NS * 2;               // NS*16 (padded: [n*16]=ab1,[n*16+1]=ab2)
    double* res   = abD + NS * 16;               // NS*3
    int* abc      = (int*)(res + NS * 3);        // NS
    int* mode     = abc + NS;                    // NS
    int* b1       = mode + NS;                   // NS
    int* k1       = b1 + NS;                     // NS
    int* poss     = k1 + NS;                     // NS
    unsigned* done = (unsigned*)(poss + NS);     // 1 (+pad to 8)
    int* cand_cnt = (int*)(done + 8);            // NS*PADI (padded counters)
    float* part   = (float*)(cand_cnt + NS * PADI);  // NS*SBPS*SLW (fully written)
    unsigned* ck  = (unsigned*)(part + (size_t)NS * SBPS * SLW);  // NS*CAP
    float* cv1    = (float*)(ck + NS * CAP);
    float* cv2    = cv1 + NS * CAP;
    (void)cv2; (void)ws_size; (void)in_sizes; (void)n_in; (void)out_size;

    // NOTE: no memset needed — k_sel1 zeroes cand_cnt and done each call,
    // and every other workspace word is written before it is read.
    k_scan1<<<dim3(SBPS, NS), 256, 0, stream>>>(outputs, labels, tmask, gd, part);
    k_sel1<<<NS, 256, 0, stream>>>(part, mode, b1, k1, poss, psum, abD, abc, s3s, s4s,
                                   cand_cnt, done);
    k_gather<<<dim3(GBPS, NS), 256, 0, stream>>>(outputs, labels, tmask, mode, b1,
                                                 cand_cnt, ck, cv1, cv2, abD);
    k_final<<<NS, 256, 0, stream>>>(outputs, labels, tmask, mode, b1, k1, poss, cand_cnt,
                                    ck, cv1, cv2, psum, abD, abc, res, s3s, s4s, done, out);
}